// Round 1
// baseline (2378.145 us; speedup 1.0000x reference)
//
#include <hip/hip_runtime.h>
#include <hip/hip_bf16.h>
#include <math.h>

#define N_PIX  50176
#define C_FEAT 4224
#define N_SEG  128
#define D_HID  1024
#define D_LOW  32
#define PCHUNK 3136   // 16 pixel-chunks * 3136 = 50176 exactly

// ---------------- workspace layout (floats) ----------------
// zeroed region: [SEG | CNT | CLS | H1 | H2]  = 803328 floats
#define OFF_SEG  0
#define OFF_CNT  540672
#define OFF_CLS  540800
#define OFF_H1   541184
#define OFF_H2   672256
#define ZERO_FLOATS 803328
#define OFF_FN   803328
#define OFF_H3   1344000
#define OFF_BEST 1348096
#define OFF_MAXV 1348224

// ---------------- K1: segment sum (dominant, HBM-bound) + histogram ----------------
__global__ __launch_bounds__(512) void k_segsum(const float* __restrict__ pixfeat,
                                                const int* __restrict__ sp,
                                                const int* __restrict__ y,
                                                float* __restrict__ seg,
                                                float* __restrict__ cnt,
                                                float* __restrict__ cls) {
  int t = threadIdx.x;
  if (blockIdx.x == 66) {
    // histogram blocks: counts + class counts
    __shared__ float hcnt[N_SEG];
    __shared__ float hcls[N_SEG * 3];
    for (int i = t; i < N_SEG; i += 512) hcnt[i] = 0.0f;
    for (int i = t; i < N_SEG * 3; i += 512) hcls[i] = 0.0f;
    __syncthreads();
    int p0 = blockIdx.y * PCHUNK;
    for (int p = p0 + t; p < p0 + PCHUNK; p += 512) {
      int s = sp[p];
      int yy = y[p];
      atomicAdd(&hcnt[s], 1.0f);
      atomicAdd(&hcls[s * 3 + yy], 1.0f);
    }
    __syncthreads();
    for (int i = t; i < N_SEG; i += 512) atomicAdd(&cnt[i], hcnt[i]);
    for (int i = t; i < N_SEG * 3; i += 512) atomicAdd(&cls[i], hcls[i]);
    return;
  }
  __shared__ float acc[N_SEG * 64];  // 32 KB
  for (int i = t; i < N_SEG * 64; i += 512) acc[i] = 0.0f;
  __syncthreads();
  int lane = t & 63;
  int w = t >> 6;  // wave id 0..7
  int chan = blockIdx.x * 64 + lane;
  int p0 = blockIdx.y * PCHUNK;
#pragma unroll 4
  for (int p = p0 + w; p < p0 + PCHUNK; p += 8) {
    int s = sp[p];
    float v = pixfeat[(size_t)p * C_FEAT + chan];
    atomicAdd(&acc[s * 64 + lane], v);
  }
  __syncthreads();
  for (int i = t; i < N_SEG * 64; i += 512) {
    float v = acc[i];
    if (v != 0.0f)
      atomicAdd(&seg[(size_t)(i >> 6) * C_FEAT + blockIdx.x * 64 + (i & 63)], v);
  }
}

// ---------------- K3: feat = seg/count (in place) + fn = feat/||feat|| ----------------
__global__ __launch_bounds__(256) void k_finalize(float* __restrict__ seg,
                                                  const float* __restrict__ cnt,
                                                  float* __restrict__ fn) {
  int row = blockIdx.x, t = threadIdx.x;
  float inv = 1.0f / fmaxf(cnt[row], 1.0f);
  float4* seg4 = (float4*)(seg + (size_t)row * C_FEAT);
  float4* fn4 = (float4*)(fn + (size_t)row * C_FEAT);
  float ss = 0.0f;
  for (int i = t; i < C_FEAT / 4; i += 256) {
    float4 v = seg4[i];
    v.x *= inv; v.y *= inv; v.z *= inv; v.w *= inv;
    seg4[i] = v;
    ss += v.x * v.x + v.y * v.y + v.z * v.z + v.w * v.w;
  }
  __shared__ float red[256];
  red[t] = ss;
  __syncthreads();
  for (int s = 128; s > 0; s >>= 1) {
    if (t < s) red[t] += red[t + s];
    __syncthreads();
  }
  float n2 = red[0];
  float rn = n2 > 0.0f ? 1.0f / sqrtf(n2) : 0.0f;
  for (int i = t; i < C_FEAT / 4; i += 256) {
    float4 v = seg4[i];
    v.x *= rn; v.y *= rn; v.z *= rn; v.w *= rn;
    fn4[i] = v;
  }
}

// ---------------- label from class counts (matches jnp.argmax first-max + fallback) ----
__device__ inline int lab0_of(const float* __restrict__ cnt, const float* __restrict__ cls, int s) {
  float c0 = cls[s * 3 + 0], c1 = cls[s * 3 + 1], c2 = cls[s * 3 + 2];
  int lab = 0;
  float bv = c0;
  if (c1 > bv) { bv = c1; lab = 1; }
  if (c2 > bv) { bv = c2; lab = 2; }
  if (lab == 0) {
    float cn = cnt[s];
    lab = (c2 > floorf(cn * 0.5f)) ? 2 : (c1 >= 1.0f ? 1 : 0);
  }
  return lab;
}

// ---------------- K5: affinity row + masked argmax ----------------
__global__ __launch_bounds__(256) void k_aff(const float* __restrict__ fn,
                                             const float* __restrict__ cnt,
                                             const float* __restrict__ cls,
                                             int* __restrict__ best,
                                             float* __restrict__ maxv) {
  __shared__ float fni[C_FEAT];
  __shared__ float part[256];
  __shared__ int labs[N_SEG];
  int i = blockIdx.x, t = threadIdx.x;
  if (t < N_SEG) labs[t] = lab0_of(cnt, cls, t);
  float4* fni4 = (float4*)fni;
  const float4* fnrow = (const float4*)(fn + (size_t)i * C_FEAT);
  for (int k = t; k < C_FEAT / 4; k += 256) fni4[k] = fnrow[k];
  __syncthreads();
  int j = t & 127, h = t >> 7;
  const float4* fnj = (const float4*)(fn + (size_t)j * C_FEAT);
  float acc = 0.0f;
  int kb = h * (C_FEAT / 8), ke = kb + (C_FEAT / 8);  // float4 units
  for (int k = kb; k < ke; k++) {
    float4 a = fni4[k];
    float4 b = fnj[k];
    acc += a.x * b.x + a.y * b.y + a.z * b.z + a.w * b.w;
  }
  part[t] = acc;
  __syncthreads();
  if (t == 0) {
    float bv = -INFINITY;
    int bi = 0;
    for (int jj = 0; jj < N_SEG; jj++) {
      float v = (labs[jj] != 0) ? (part[jj] + part[jj + 128]) : -INFINITY;
      if (v > bv) { bv = v; bi = jj; }
    }
    best[i] = bi;
    maxv[i] = bv;
  }
}

// ---------------- split-K fp32 GEMM: C(128 x N) += A(128 x Kchunk) * W ----------------
__global__ __launch_bounds__(256) void k_gemm(const float* __restrict__ A,
                                              const float* __restrict__ W,
                                              float* __restrict__ C,
                                              int K, int N, int KC) {
  __shared__ float As[128 * 64];  // 32 KB
  __shared__ float Ws[64 * 64];   // 16 KB
  int t = threadIdx.x;
  int n0 = blockIdx.x * 64;
  int k0 = blockIdx.y * KC;
  int k1 = min(k0 + KC, K);
  int cp = t & 31, rg = t >> 5;
  float acc[16][2];
#pragma unroll
  for (int r = 0; r < 16; r++) { acc[r][0] = 0.0f; acc[r][1] = 0.0f; }

  for (int ks = k0; ks < k1; ks += 64) {
    // stage A tile: 128 rows x 64 k
    {
      int rr = t >> 4, kq = t & 15;
      const float4* Ag = (const float4*)A;
#pragma unroll
      for (int rep = 0; rep < 8; rep++) {
        int r = rr + rep * 16;
        float4 v = Ag[((size_t)r * K + ks) / 4 + kq];
        ((float4*)As)[r * 16 + kq] = v;
      }
      int kk = t >> 4, cq = t & 15;
      const float4* Wg = (const float4*)W;
#pragma unroll
      for (int rep = 0; rep < 4; rep++) {
        int k = kk + rep * 16;
        float4 v = Wg[((size_t)(ks + k) * N + n0) / 4 + cq];
        ((float4*)Ws)[k * 16 + cq] = v;
      }
    }
    __syncthreads();
#pragma unroll 2
    for (int kk4 = 0; kk4 < 16; kk4++) {
      float2 w[4];
#pragma unroll
      for (int jj = 0; jj < 4; jj++) w[jj] = ((float2*)Ws)[(kk4 * 4 + jj) * 32 + cp];
#pragma unroll
      for (int r = 0; r < 16; r++) {
        float4 a = ((float4*)As)[(rg * 16 + r) * 16 + kk4];
        acc[r][0] += a.x * w[0].x + a.y * w[1].x + a.z * w[2].x + a.w * w[3].x;
        acc[r][1] += a.x * w[0].y + a.y * w[1].y + a.z * w[2].y + a.w * w[3].y;
      }
    }
    __syncthreads();
  }
#pragma unroll
  for (int r = 0; r < 16; r++) {
    int row = rg * 16 + r;
    atomicAdd(&C[(size_t)row * N + n0 + 2 * cp + 0], acc[r][0]);
    atomicAdd(&C[(size_t)row * N + n0 + 2 * cp + 1], acc[r][1]);
  }
}

// ---------------- bias + relu ----------------
__global__ __launch_bounds__(256) void k_bias_relu(float* __restrict__ h,
                                                   const float* __restrict__ b,
                                                   int nmask, int total) {
  int i = blockIdx.x * 256 + threadIdx.x;
  if (i < total) h[i] = fmaxf(h[i] + b[i & nmask], 0.0f);
}

// ---------------- layer 3: h3 = relu(h2 @ w3 + b3), 128x1024 @ 1024x32 ----------------
__global__ __launch_bounds__(256) void k_l3(const float* __restrict__ h2,
                                            const float* __restrict__ w3,
                                            const float* __restrict__ b3,
                                            float* __restrict__ h3) {
  int row = blockIdx.x, t = threadIdx.x;
  int c = t & 31, kh = t >> 5;  // 8 chunks of 128
  float acc = 0.0f;
  const float* hrow = h2 + (size_t)row * D_HID;
  for (int k = kh * 128; k < kh * 128 + 128; k++) acc += hrow[k] * w3[k * 32 + c];
  __shared__ float red[256];
  red[t] = acc;
  __syncthreads();
  if (t < 32) {
    float s = 0.0f;
#pragma unroll
    for (int g = 0; g < 8; g++) s += red[g * 32 + c];
    h3[row * 32 + c] = fmaxf(s + b3[c], 0.0f);
  }
}

// ---------------- final: logits+softmax -> probs; label propagation -> lab ----------------
__global__ __launch_bounds__(256) void k_final(const float* __restrict__ h3,
                                               const float* __restrict__ wc,
                                               const float* __restrict__ bc,
                                               const float* __restrict__ cnt,
                                               const float* __restrict__ cls,
                                               const int* __restrict__ best,
                                               const float* __restrict__ maxv,
                                               float* __restrict__ out) {
  __shared__ int labs[N_SEG];
  int t = threadIdx.x;
  if (t < N_SEG) labs[t] = lab0_of(cnt, cls, t);
  __syncthreads();
  if (t < N_SEG) {
    int i = t;
    float l0 = bc[0], l1 = bc[1];
#pragma unroll
    for (int k = 0; k < D_LOW; k++) {
      float h = h3[i * D_LOW + k];
      l0 += h * wc[k * 2 + 0];
      l1 += h * wc[k * 2 + 1];
    }
    float m = fmaxf(l0, l1);
    float e0 = expf(l0 - m), e1 = expf(l1 - m);
    float inv = 1.0f / (e0 + e1);
    out[i * 2 + 0] = e0 * inv;
    out[i * 2 + 1] = e1 * inv;
    int lab = labs[i];
    if (lab == 0 && maxv[i] > 0.8f) lab = labs[best[i]];
    out[N_SEG * 2 + i] = (float)lab;
  }
}

extern "C" void kernel_launch(void* const* d_in, const int* in_sizes, int n_in,
                              void* d_out, int out_size, void* d_ws, size_t ws_size,
                              hipStream_t stream) {
  const float* pixfeat = (const float*)d_in[0];
  const float* w1 = (const float*)d_in[1];
  const float* b1 = (const float*)d_in[2];
  const float* w2 = (const float*)d_in[3];
  const float* b2 = (const float*)d_in[4];
  const float* w3 = (const float*)d_in[5];
  const float* b3 = (const float*)d_in[6];
  const float* wc = (const float*)d_in[7];
  const float* bc = (const float*)d_in[8];
  const int* sp = (const int*)d_in[9];
  const int* y = (const int*)d_in[10];
  float* out = (float*)d_out;

  float* ws = (float*)d_ws;
  float* SEG = ws + OFF_SEG;    // feat after k_finalize
  float* CNT = ws + OFF_CNT;
  float* CLS = ws + OFF_CLS;
  float* H1 = ws + OFF_H1;
  float* H2 = ws + OFF_H2;
  float* FN = ws + OFF_FN;
  float* H3 = ws + OFF_H3;
  int* BEST = (int*)(ws + OFF_BEST);
  float* MAXV = ws + OFF_MAXV;

  // zero the atomic-accumulated buffers
  hipMemsetAsync(d_ws, 0, (size_t)ZERO_FLOATS * sizeof(float), stream);

  // segment sums (dominant) + histogram blocks
  dim3 g1(67, 16);
  k_segsum<<<g1, 512, 0, stream>>>(pixfeat, sp, y, SEG, CNT, CLS);

  // feat + fn
  k_finalize<<<128, 256, 0, stream>>>(SEG, CNT, FN);

  // affinity argmax (per-row)
  k_aff<<<128, 256, 0, stream>>>(FN, CNT, CLS, BEST, MAXV);

  // MLP layer 1: feat(128x4224) @ w1(4224x1024)
  dim3 gg1(16, 17);
  k_gemm<<<gg1, 256, 0, stream>>>(SEG, w1, H1, C_FEAT, D_HID, 256);
  k_bias_relu<<<512, 256, 0, stream>>>(H1, b1, D_HID - 1, 128 * D_HID);

  // MLP layer 2: h1 @ w2(1024x1024)
  dim3 gg2(16, 16);
  k_gemm<<<gg2, 256, 0, stream>>>(H1, w2, H2, D_HID, D_HID, 64);
  k_bias_relu<<<512, 256, 0, stream>>>(H2, b2, D_HID - 1, 128 * D_HID);

  // MLP layer 3
  k_l3<<<128, 256, 0, stream>>>(H2, w3, b3, H3);

  // classifier + softmax + label propagation
  k_final<<<1, 256, 0, stream>>>(H3, wc, bc, CNT, CLS, BEST, MAXV, out);
}

// Round 2
// 1370.963 us; speedup vs baseline: 1.7347x; 1.7347x over previous
//
#include <hip/hip_runtime.h>
#include <math.h>

#define N_PIX  50176
#define C_FEAT 4224
#define N_SEG  128
#define D_HID  1024
#define D_LOW  32

// ---------------- workspace layout (float indices) ----------------
#define OFF_FEAT  0
#define OFF_FN    540672
#define OFF_CNT   1081344
#define OFF_CLS   1081472
#define OFF_BASE  1081856
#define OFF_CUR   1081984
#define OFF_ORDER 1082112
#define OFF_H1P   1132288   // 11 * 131072
#define OFF_H2P   1132288   // aliases H1P (dead by the time gemm2 runs)
#define OFF_H1    2574080
#define OFF_H2    2705152
#define OFF_H3    2836224
#define OFF_BEST  2840320
#define OFF_MAXV  2840448

// ---------------- K0: histograms (counts + class counts) ----------------
__global__ __launch_bounds__(512) void k_hist(const int* __restrict__ sp,
                                              const int* __restrict__ y,
                                              float* __restrict__ cnt,
                                              float* __restrict__ cls) {
  __shared__ float hcnt[N_SEG];
  __shared__ float hcls[N_SEG * 3];
  int t = threadIdx.x;
  if (t < N_SEG) hcnt[t] = 0.0f;
  if (t < N_SEG * 3) hcls[t] = 0.0f;
  __syncthreads();
  int p = blockIdx.x * 512 + t;
  int s = sp[p];
  int yy = y[p];
  atomicAdd(&hcnt[s], 1.0f);
  atomicAdd(&hcls[s * 3 + yy], 1.0f);
  __syncthreads();
  if (t < N_SEG) atomicAdd(&cnt[t], hcnt[t]);
  if (t < N_SEG * 3) atomicAdd(&cls[t], hcls[t]);
}

// ---------------- K1: prefix sum -> base offsets + cursors ----------------
__global__ __launch_bounds__(128) void k_prefix(const float* __restrict__ cnt,
                                                int* __restrict__ base,
                                                int* __restrict__ cur) {
  if (threadIdx.x == 0) {
    int s = 0;
    for (int i = 0; i < N_SEG; i++) {
      base[i] = s;
      cur[i] = s;
      s += (int)cnt[i];
    }
  }
}

// ---------------- K2: scatter pixel ids into segment-sorted order ----------------
__global__ __launch_bounds__(512) void k_scatter(const int* __restrict__ sp,
                                                 int* __restrict__ cur,
                                                 int* __restrict__ order) {
  int p = blockIdx.x * 512 + threadIdx.x;
  int s = sp[p];
  int pos = atomicAdd(&cur[s], 1);
  order[pos] = p;
}

// ---------------- K3: gather segment-mean (dominant, HBM-bound, NO atomics) ----
__global__ __launch_bounds__(256) void k_gather(const float* __restrict__ pixfeat,
                                                const int* __restrict__ order,
                                                const int* __restrict__ base,
                                                const float* __restrict__ cnt,
                                                float* __restrict__ feat) {
  int s = blockIdx.y;
  int cb = blockIdx.x;            // 33 slabs of 128 channels
  int t = threadIdx.x;
  int lane = t & 63, w = t >> 6;  // 4 waves
  int b0 = base[s];
  int n = (int)cnt[s];
  const float2* src = (const float2*)pixfeat;
  size_t coff = (size_t)cb * 64 + lane;  // float2 index within a row
  float ax = 0.0f, ay = 0.0f;
#pragma unroll 8
  for (int i = w; i < n; i += 4) {
    int p = order[b0 + i];
    float2 v = src[(size_t)p * (C_FEAT / 2) + coff];
    ax += v.x;
    ay += v.y;
  }
  __shared__ float red[4][128];
  ((float2*)(&red[w][0]))[lane] = make_float2(ax, ay);
  __syncthreads();
  if (t < 128) {
    float inv = 1.0f / fmaxf((float)n, 1.0f);
    float v = (red[0][t] + red[1][t] + red[2][t] + red[3][t]) * inv;
    feat[(size_t)s * C_FEAT + cb * 128 + t] = v;
  }
}

// ---------------- K4: fn = feat / ||feat|| ----------------
__global__ __launch_bounds__(256) void k_norm(const float* __restrict__ feat,
                                              float* __restrict__ fn) {
  int row = blockIdx.x, t = threadIdx.x;
  const float4* f4 = (const float4*)(feat + (size_t)row * C_FEAT);
  float4* fn4 = (float4*)(fn + (size_t)row * C_FEAT);
  float ss = 0.0f;
  for (int i = t; i < C_FEAT / 4; i += 256) {
    float4 v = f4[i];
    ss += v.x * v.x + v.y * v.y + v.z * v.z + v.w * v.w;
  }
  __shared__ float red[256];
  red[t] = ss;
  __syncthreads();
  for (int s = 128; s > 0; s >>= 1) {
    if (t < s) red[t] += red[t + s];
    __syncthreads();
  }
  float n2 = red[0];
  float rn = n2 > 0.0f ? 1.0f / sqrtf(n2) : 0.0f;
  for (int i = t; i < C_FEAT / 4; i += 256) {
    float4 v = f4[i];
    v.x *= rn; v.y *= rn; v.z *= rn; v.w *= rn;
    fn4[i] = v;
  }
}

// ---------------- label from class counts ----------------
__device__ inline int lab0_of(const float* __restrict__ cnt, const float* __restrict__ cls, int s) {
  float c0 = cls[s * 3 + 0], c1 = cls[s * 3 + 1], c2 = cls[s * 3 + 2];
  int lab = 0;
  float bv = c0;
  if (c1 > bv) { bv = c1; lab = 1; }
  if (c2 > bv) { bv = c2; lab = 2; }
  if (lab == 0) {
    float cn = cnt[s];
    lab = (c2 > floorf(cn * 0.5f)) ? 2 : (c1 >= 1.0f ? 1 : 0);
  }
  return lab;
}

// ---------------- K5: affinity row + masked argmax ----------------
__global__ __launch_bounds__(256) void k_aff(const float* __restrict__ fn,
                                             const float* __restrict__ cnt,
                                             const float* __restrict__ cls,
                                             int* __restrict__ best,
                                             float* __restrict__ maxv) {
  __shared__ float fni[C_FEAT];
  __shared__ float part[256];
  __shared__ int labs[N_SEG];
  int i = blockIdx.x, t = threadIdx.x;
  if (t < N_SEG) labs[t] = lab0_of(cnt, cls, t);
  float4* fni4 = (float4*)fni;
  const float4* fnrow = (const float4*)(fn + (size_t)i * C_FEAT);
  for (int k = t; k < C_FEAT / 4; k += 256) fni4[k] = fnrow[k];
  __syncthreads();
  int j = t & 127, h = t >> 7;
  const float4* fnj = (const float4*)(fn + (size_t)j * C_FEAT);
  float acc = 0.0f;
  int kb = h * (C_FEAT / 8), ke = kb + (C_FEAT / 8);
  for (int k = kb; k < ke; k++) {
    float4 a = fni4[k];
    float4 b = fnj[k];
    acc += a.x * b.x + a.y * b.y + a.z * b.z + a.w * b.w;
  }
  part[t] = acc;
  __syncthreads();
  if (t == 0) {
    float bv = -INFINITY;
    int bi = 0;
    for (int jj = 0; jj < N_SEG; jj++) {
      float v = (labs[jj] != 0) ? (part[jj] + part[jj + 128]) : -INFINITY;
      if (v > bv) { bv = v; bi = jj; }
    }
    best[i] = bi;
    maxv[i] = bv;
  }
}

// ---------------- split-K fp32 GEMM into per-split partial buffers ----------------
__global__ __launch_bounds__(256) void k_gemm(const float* __restrict__ A,
                                              const float* __restrict__ W,
                                              float* __restrict__ HP,
                                              int K, int N, int KC) {
  __shared__ float As[128 * 64];
  __shared__ float Ws[64 * 64];
  int t = threadIdx.x;
  int n0 = blockIdx.x * 64;
  int k0 = blockIdx.y * KC;
  int k1 = min(k0 + KC, K);
  float* Cp = HP + (size_t)blockIdx.y * (128 * (size_t)N);
  int cp = t & 31, rg = t >> 5;
  float acc[16][2];
#pragma unroll
  for (int r = 0; r < 16; r++) { acc[r][0] = 0.0f; acc[r][1] = 0.0f; }

  for (int ks = k0; ks < k1; ks += 64) {
    {
      int rr = t >> 4, kq = t & 15;
      const float4* Ag = (const float4*)A;
#pragma unroll
      for (int rep = 0; rep < 8; rep++) {
        int r = rr + rep * 16;
        float4 v = Ag[((size_t)r * K + ks) / 4 + kq];
        ((float4*)As)[r * 16 + kq] = v;
      }
      int kk = t >> 4, cq = t & 15;
      const float4* Wg = (const float4*)W;
#pragma unroll
      for (int rep = 0; rep < 4; rep++) {
        int k = kk + rep * 16;
        float4 v = Wg[((size_t)(ks + k) * N + n0) / 4 + cq];
        ((float4*)Ws)[k * 16 + cq] = v;
      }
    }
    __syncthreads();
#pragma unroll 2
    for (int kk4 = 0; kk4 < 16; kk4++) {
      float2 w[4];
#pragma unroll
      for (int jj = 0; jj < 4; jj++) w[jj] = ((float2*)Ws)[(kk4 * 4 + jj) * 32 + cp];
#pragma unroll
      for (int r = 0; r < 16; r++) {
        float4 a = ((float4*)As)[(rg * 16 + r) * 16 + kk4];
        acc[r][0] += a.x * w[0].x + a.y * w[1].x + a.z * w[2].x + a.w * w[3].x;
        acc[r][1] += a.x * w[0].y + a.y * w[1].y + a.z * w[2].y + a.w * w[3].y;
      }
    }
    __syncthreads();
  }
#pragma unroll
  for (int r = 0; r < 16; r++) {
    int row = rg * 16 + r;
    ((float2*)(Cp + (size_t)row * N))[n0 / 2 + cp] = make_float2(acc[r][0], acc[r][1]);
  }
}

// ---------------- reduce splits + bias + relu ----------------
__global__ __launch_bounds__(256) void k_reduce_bias_relu(float* __restrict__ h,
                                                          const float* __restrict__ hp,
                                                          const float* __restrict__ b,
                                                          int S, int nmask, int total) {
  int i = blockIdx.x * 256 + threadIdx.x;
  if (i < total) {
    float s = 0.0f;
    for (int k = 0; k < S; k++) s += hp[(size_t)k * total + i];
    h[i] = fmaxf(s + b[i & nmask], 0.0f);
  }
}

// ---------------- layer 3 ----------------
__global__ __launch_bounds__(256) void k_l3(const float* __restrict__ h2,
                                            const float* __restrict__ w3,
                                            const float* __restrict__ b3,
                                            float* __restrict__ h3) {
  int row = blockIdx.x, t = threadIdx.x;
  int c = t & 31, kh = t >> 5;
  float acc = 0.0f;
  const float* hrow = h2 + (size_t)row * D_HID;
  for (int k = kh * 128; k < kh * 128 + 128; k++) acc += hrow[k] * w3[k * 32 + c];
  __shared__ float red[256];
  red[t] = acc;
  __syncthreads();
  if (t < 32) {
    float s = 0.0f;
#pragma unroll
    for (int g = 0; g < 8; g++) s += red[g * 32 + c];
    h3[row * 32 + c] = fmaxf(s + b3[c], 0.0f);
  }
}

// ---------------- final: softmax probs + label propagation ----------------
__global__ __launch_bounds__(256) void k_final(const float* __restrict__ h3,
                                               const float* __restrict__ wc,
                                               const float* __restrict__ bc,
                                               const float* __restrict__ cnt,
                                               const float* __restrict__ cls,
                                               const int* __restrict__ best,
                                               const float* __restrict__ maxv,
                                               float* __restrict__ out) {
  __shared__ int labs[N_SEG];
  int t = threadIdx.x;
  if (t < N_SEG) labs[t] = lab0_of(cnt, cls, t);
  __syncthreads();
  if (t < N_SEG) {
    int i = t;
    float l0 = bc[0], l1 = bc[1];
#pragma unroll
    for (int k = 0; k < D_LOW; k++) {
      float h = h3[i * D_LOW + k];
      l0 += h * wc[k * 2 + 0];
      l1 += h * wc[k * 2 + 1];
    }
    float m = fmaxf(l0, l1);
    float e0 = expf(l0 - m), e1 = expf(l1 - m);
    float inv = 1.0f / (e0 + e1);
    out[i * 2 + 0] = e0 * inv;
    out[i * 2 + 1] = e1 * inv;
    int lab = labs[i];
    if (lab == 0 && maxv[i] > 0.8f) lab = labs[best[i]];
    out[N_SEG * 2 + i] = (float)lab;
  }
}

extern "C" void kernel_launch(void* const* d_in, const int* in_sizes, int n_in,
                              void* d_out, int out_size, void* d_ws, size_t ws_size,
                              hipStream_t stream) {
  const float* pixfeat = (const float*)d_in[0];
  const float* w1 = (const float*)d_in[1];
  const float* b1 = (const float*)d_in[2];
  const float* w2 = (const float*)d_in[3];
  const float* b2 = (const float*)d_in[4];
  const float* w3 = (const float*)d_in[5];
  const float* b3 = (const float*)d_in[6];
  const float* wc = (const float*)d_in[7];
  const float* bc = (const float*)d_in[8];
  const int* sp = (const int*)d_in[9];
  const int* y = (const int*)d_in[10];
  float* out = (float*)d_out;

  float* ws = (float*)d_ws;
  float* FEAT = ws + OFF_FEAT;
  float* FN = ws + OFF_FN;
  float* CNT = ws + OFF_CNT;
  float* CLS = ws + OFF_CLS;
  int* BASE = (int*)(ws + OFF_BASE);
  int* CUR = (int*)(ws + OFF_CUR);
  int* ORDER = (int*)(ws + OFF_ORDER);
  float* H1P = ws + OFF_H1P;
  float* H2P = ws + OFF_H2P;
  float* H1 = ws + OFF_H1;
  float* H2 = ws + OFF_H2;
  float* H3 = ws + OFF_H3;
  int* BEST = (int*)(ws + OFF_BEST);
  float* MAXV = ws + OFF_MAXV;

  // zero only the atomic-accumulated histograms (CNT|CLS contiguous, 512 floats)
  hipMemsetAsync(CNT, 0, 512 * sizeof(float), stream);

  k_hist<<<N_PIX / 512, 512, 0, stream>>>(sp, y, CNT, CLS);
  k_prefix<<<1, 128, 0, stream>>>(CNT, BASE, CUR);
  k_scatter<<<N_PIX / 512, 512, 0, stream>>>(sp, CUR, ORDER);

  // dominant: segment mean via gather, no atomics
  dim3 gg(33, 128);
  k_gather<<<gg, 256, 0, stream>>>(pixfeat, ORDER, BASE, CNT, FEAT);

  k_norm<<<128, 256, 0, stream>>>(FEAT, FN);
  k_aff<<<128, 256, 0, stream>>>(FN, CNT, CLS, BEST, MAXV);

  // MLP layer 1: feat(128x4224) @ w1 -> 11 splits of KC=384
  dim3 g1(16, 11);
  k_gemm<<<g1, 256, 0, stream>>>(FEAT, w1, H1P, C_FEAT, D_HID, 384);
  k_reduce_bias_relu<<<512, 256, 0, stream>>>(H1, H1P, b1, 11, D_HID - 1, 128 * D_HID);

  // MLP layer 2: h1 @ w2 -> 8 splits of KC=128
  dim3 g2(16, 8);
  k_gemm<<<g2, 256, 0, stream>>>(H1, w2, H2P, D_HID, D_HID, 128);
  k_reduce_bias_relu<<<512, 256, 0, stream>>>(H2, H2P, b2, 8, D_HID - 1, 128 * D_HID);

  k_l3<<<128, 256, 0, stream>>>(H2, w3, b3, H3);
  k_final<<<1, 256, 0, stream>>>(H3, wc, bc, CNT, CLS, BEST, MAXV, out);
}